// Round 10
// baseline (1493.781 us; speedup 1.0000x reference)
//
#include <hip/hip_runtime.h>
#include <hip/hip_bf16.h>

#define N_ATOMS   500000
#define N_BONDS   1000000
#define MAX_NB    6
#define ATOM_FDIM 133
#define BOND_FDIM 14
#define HIDDEN    128
#define N_MOLS    25000
#define APM       20

typedef __attribute__((ext_vector_type(8))) short short8;
typedef __attribute__((ext_vector_type(4))) float f32x4;
typedef unsigned short u16;
typedef unsigned int   u32;

__device__ __forceinline__ float bf2f(u16 u) {
    u32 t = ((u32)u) << 16;
    return __builtin_bit_cast(float, t);
}
__device__ __forceinline__ u16 f2bf(float f) {
    u32 t = __builtin_bit_cast(u32, f);
    t += 0x7FFFu + ((t >> 16) & 1u);
    return (u16)(t >> 16);
}
__device__ __forceinline__ u32 pk2(float a, float b) {
    return (u32)f2bf(a) | ((u32)f2bf(b) << 16);
}

// async global->LDS, 16B per lane (W staging only).
__device__ __forceinline__ void gl16(const u16* g, u16* l) {
    __builtin_amdgcn_global_load_lds(
        (__attribute__((address_space(1))) void*)(g),
        (__attribute__((address_space(3))) void*)(l), 16, 0, 0);
}

// ---------------- weight prep: fp32 -> padded bf16 ----------------
__global__ void prep_weights(const float* __restrict__ Wi, const float* __restrict__ Wh,
                             const float* __restrict__ Wo,
                             u16* __restrict__ Wip, u16* __restrict__ Whp, u16* __restrict__ Wop) {
    int stride = gridDim.x * blockDim.x;
    int tid = blockIdx.x * blockDim.x + threadIdx.x;
    for (int i = tid; i < 128 * 160; i += stride) {
        int r = i / 160, c = i % 160;
        Wip[i] = (c < 133) ? f2bf(Wi[r * 133 + c]) : (u16)0;
        Whp[i] = (c < 142) ? f2bf(Wh[r * 142 + c]) : (u16)0;
    }
    for (int i = tid; i < 128 * 288; i += stride) {
        int r = i / 288, c = i % 288;
        float v = 0.f;
        if (c < 133)      v = Wo[r * 261 + c];
        else if (c >= 160) v = Wo[r * 261 + (c - 27)];
        Wop[i] = f2bf(v);
    }
}

// ---------------- bond pre-sum: sum_j f_bonds[a2b[:,j]] -> bf16 [N][32] ----------------
__global__ __launch_bounds__(256) void bond_gather(const float* __restrict__ fb, const int* __restrict__ a2b,
                                                   u16* __restrict__ outp) {
    long t = (long)blockIdx.x * 256 + threadIdx.x;
    int atom = (int)(t >> 4);
    int c2   = (int)(t & 15);
    if (atom >= N_ATOMS) return;
    int c0 = 2 * c2, c1 = c0 + 1;
    float s0 = 0.f, s1 = 0.f;
    if (c0 < BOND_FDIM) {
#pragma unroll
        for (int j = 0; j < MAX_NB; j++) {
            int idx = a2b[atom * 6 + j];
            const float* row = fb + (long)idx * BOND_FDIM;
            s0 += row[c0];
            if (c1 < BOND_FDIM) s1 += row[c1];
        }
    }
    *(u32*)(outp + (long)atom * 32 + c0) = pk2(s0, s1);
}

// ---------------- gather-relu-sum: dst[a] = sum_j relu(src[a2a[a,j]]) (bf16 128-wide) ---
__global__ __launch_bounds__(256) void gather_relu_sum(const u16* __restrict__ src,
                                                       const int* __restrict__ a2a,
                                                       u16* __restrict__ dst) {
    long t = (long)blockIdx.x * 256 + threadIdx.x;
    int atom = (int)(t >> 4);
    int c8   = (int)(t & 15) << 3;
    float s[8] = {0, 0, 0, 0, 0, 0, 0, 0};
#pragma unroll
    for (int j = 0; j < MAX_NB; j++) {
        int idx = a2a[atom * 6 + j];
        uint4 v = *(const uint4*)(src + (long)idx * 128 + c8);
        u32 w[4] = {v.x, v.y, v.z, v.w};
#pragma unroll
        for (int q = 0; q < 4; q++) {
            s[2 * q]     += fmaxf(__builtin_bit_cast(float, w[q] << 16), 0.f);
            s[2 * q + 1] += fmaxf(__builtin_bit_cast(float, w[q] & 0xFFFF0000u), 0.f);
        }
    }
    uint4 o;
    o.x = pk2(s[0], s[1]);
    o.y = pk2(s[2], s[3]);
    o.z = pk2(s[4], s[5]);
    o.w = pk2(s[6], s[7]);
    *(uint4*)(dst + (long)atom * 128 + c8) = o;
}

// ---------------- TLP GEMM: wave-independent 16-row tiles ----------------
// Out[N][128] = concat(A0,A1)[N][32*KB] @ Wp^T (+bias) (+Xadd), swapped-operand MFMA.
// W staged once per block into LDS (fragment-linear, conflict-free ds_read_b128).
// Each wave grid-strides over tiles: issue all A(+X) loads (small fixed register
// arrays -> allocator keeps them), one natural wait, MFMA, store. Latency hiding
// comes from 8-16 independent waves/CU, NOT per-wave pipelining (which the
// compiler demoted in r3/r4/r5/r9 -> the 2.8 TB/s wall).
template <int KB0, int KB1, bool ADDX, bool BIAS>
__global__ __launch_bounds__(256, 4) void gemm_tlp(
    const u16* __restrict__ A0, int ldA0,
    const u16* __restrict__ A1, int ldA1,
    const u16* __restrict__ Wp, const float* __restrict__ bias,
    const u16* __restrict__ Xadd, u16* __restrict__ Out) {
    constexpr int KB = KB0 + KB1;
    constexpr int KP = KB * 32;
    constexpr int WSLOTS = KB * 8;
    constexpr long NTILE = N_ATOMS / 16;  // 31250, exact
    __shared__ __align__(16) u16 WL[WSLOTS * 512];

    const int lane = threadIdx.x & 63;
    const int wave = threadIdx.x >> 6;
    const int lrow = lane & 15;
    const int kg   = lane >> 4;

    for (int s = wave; s < WSLOTS; s += 4) {
        int kb = s >> 3, n = s & 7;
        gl16(Wp + (n * 16 + lrow) * KP + kb * 32 + kg * 8, WL + s * 512);
    }
    asm volatile("s_waitcnt vmcnt(0)" ::: "memory");
    __syncthreads();

    const long TW = (long)gridDim.x * 4;
#pragma unroll 1
    for (long tile = (long)blockIdx.x * 4 + wave; tile < NTILE; tile += TW) {
        const long r = tile * 16 + lrow;

        uint4 a[KB];
        if constexpr (KB0 > 0) {
            const u16* p = A0 + r * (long)ldA0 + kg * 8;
#pragma unroll
            for (int kb = 0; kb < KB0; kb++) a[kb] = *(const uint4*)(p + kb * 32);
        }
        if constexpr (KB1 > 0) {
            const u16* p = A1 + r * (long)ldA1 + kg * 8;
#pragma unroll
            for (int kb = 0; kb < KB1; kb++) a[KB0 + kb] = *(const uint4*)(p + kb * 32);
        }
        uint2 xv[ADDX ? 8 : 1];
        if constexpr (ADDX) {
#pragma unroll
            for (int n = 0; n < 8; n++)
                xv[n] = *(const uint2*)(Xadd + r * 128 + n * 16 + kg * 4);
        }

        f32x4 acc[8];
#pragma unroll
        for (int n = 0; n < 8; n++) acc[n] = (f32x4){0.f, 0.f, 0.f, 0.f};
#pragma unroll
        for (int kb = 0; kb < KB; kb++) {
            short8 af = __builtin_bit_cast(short8, a[kb]);
#pragma unroll
            for (int n = 0; n < 8; n++) {
                short8 bf = *(const short8*)(WL + (kb * 8 + n) * 512 + lane * 8);
                acc[n] = __builtin_amdgcn_mfma_f32_16x16x32_bf16(bf, af, acc[n], 0, 0, 0);
            }
        }

#pragma unroll
        for (int n = 0; n < 8; n++) {
            float v0 = acc[n][0], v1 = acc[n][1], v2 = acc[n][2], v3 = acc[n][3];
            if constexpr (BIAS) {
                float4 b4 = *(const float4*)(bias + n * 16 + kg * 4);
                v0 += b4.x; v1 += b4.y; v2 += b4.z; v3 += b4.w;
            }
            if constexpr (ADDX) {
                v0 += __builtin_bit_cast(float, xv[n].x << 16);
                v1 += __builtin_bit_cast(float, xv[n].x & 0xFFFF0000u);
                v2 += __builtin_bit_cast(float, xv[n].y << 16);
                v3 += __builtin_bit_cast(float, xv[n].y & 0xFFFF0000u);
            }
            uint2 o;
            o.x = pk2(v0, v1);
            o.y = pk2(v2, v3);
            *(uint2*)(Out + r * 128 + n * 16 + kg * 4) = o;
        }
    }
}

// ---------------- fused Wi GEMM + fa conversion (TLP style) ----------------
// Reads f_atoms fp32 directly, converts to bf16 fragments in-register, computes
// x = fa@Wi^T + bi AND writes padded bf16 fa[N][160] (consumed by the Wo GEMM).
__global__ __launch_bounds__(256, 4) void gemm_wi(
    const float* __restrict__ FA, const u16* __restrict__ Wp,
    const float* __restrict__ bias, u16* __restrict__ fa16, u16* __restrict__ Out) {
    constexpr int KB = 5, KP = 160;
    constexpr int WSLOTS = KB * 8;
    constexpr long NTILE = N_ATOMS / 16;
    __shared__ __align__(16) u16 WL[WSLOTS * 512];

    const int lane = threadIdx.x & 63;
    const int wave = threadIdx.x >> 6;
    const int lrow = lane & 15;
    const int kg   = lane >> 4;

    for (int s = wave; s < WSLOTS; s += 4) {
        int kb = s >> 3, n = s & 7;
        gl16(Wp + (n * 16 + lrow) * KP + kb * 32 + kg * 8, WL + s * 512);
    }
    asm volatile("s_waitcnt vmcnt(0)" ::: "memory");
    __syncthreads();

    const long TW = (long)gridDim.x * 4;
#pragma unroll 1
    for (long tile = (long)blockIdx.x * 4 + wave; tile < NTILE; tile += TW) {
        const long r = tile * 16 + lrow;
        const float* p = FA + r * (long)ATOM_FDIM + kg * 8;

        uint4 af32[4][2];
#pragma unroll
        for (int kb = 0; kb < 4; kb++) {
            af32[kb][0] = *(const uint4*)(p + kb * 32);
            af32[kb][1] = *(const uint4*)(p + kb * 32 + 4);
        }
        uint4 a4 = (uint4){0, 0, 0, 0};
        float a4s = 0.f;
        if (kg == 0) {
            const float* q = FA + r * (long)ATOM_FDIM + 128;
            a4  = *(const uint4*)(q);
            a4s = q[4];
        }

        short8 frag[5];
#pragma unroll
        for (int kb = 0; kb < 4; kb++) {
            float4 lo = __builtin_bit_cast(float4, af32[kb][0]);
            float4 hi = __builtin_bit_cast(float4, af32[kb][1]);
            uint4 pk;
            pk.x = pk2(lo.x, lo.y);
            pk.y = pk2(lo.z, lo.w);
            pk.z = pk2(hi.x, hi.y);
            pk.w = pk2(hi.z, hi.w);
            frag[kb] = __builtin_bit_cast(short8, pk);
        }
        {
            uint4 pk = (uint4){0, 0, 0, 0};
            if (kg == 0) {
                float4 q = __builtin_bit_cast(float4, a4);
                pk.x = pk2(q.x, q.y);
                pk.y = pk2(q.z, q.w);
                pk.z = pk2(a4s, 0.f);
            }
            frag[4] = __builtin_bit_cast(short8, pk);
        }

        f32x4 acc[8];
#pragma unroll
        for (int n = 0; n < 8; n++) acc[n] = (f32x4){0.f, 0.f, 0.f, 0.f};
#pragma unroll
        for (int kb = 0; kb < 5; kb++) {
#pragma unroll
            for (int n = 0; n < 8; n++) {
                short8 bf = *(const short8*)(WL + (kb * 8 + n) * 512 + lane * 8);
                acc[n] = __builtin_amdgcn_mfma_f32_16x16x32_bf16(bf, frag[kb], acc[n], 0, 0, 0);
            }
        }

#pragma unroll
        for (int kb = 0; kb < 5; kb++)
            *(uint4*)(fa16 + r * 160 + kb * 32 + kg * 8) = __builtin_bit_cast(uint4, frag[kb]);
#pragma unroll
        for (int n = 0; n < 8; n++) {
            float4 b4 = *(const float4*)(bias + n * 16 + kg * 4);
            uint2 o;
            o.x = pk2(acc[n][0] + b4.x, acc[n][1] + b4.y);
            o.y = pk2(acc[n][2] + b4.z, acc[n][3] + b4.w);
            *(uint2*)(Out + r * 128 + n * 16 + kg * 4) = o;
        }
    }
}

// ---------------- readout: per-mol max over 20 atoms (w/ relu) then dot ffn_w ----------
__global__ __launch_bounds__(256) void readout(const u16* __restrict__ ah,
                                               const float* __restrict__ ffn_w,
                                               const float* __restrict__ ffn_b,
                                               float* __restrict__ out) {
    int mol  = blockIdx.x * 4 + (threadIdx.x >> 6);
    int lane = threadIdx.x & 63;
    if (mol >= N_MOLS) return;
    float m0 = -1e30f, m1 = -1e30f;
    const u16* base = ah + (long)mol * APM * 128 + 2 * lane;
#pragma unroll
    for (int a = 0; a < APM; a++) {
        u32 v = *(const u32*)(base + a * 128);
        m0 = fmaxf(m0, bf2f((u16)(v & 0xFFFFu)));
        m1 = fmaxf(m1, bf2f((u16)(v >> 16)));
    }
    m0 = fmaxf(m0, 0.f);
    m1 = fmaxf(m1, 0.f);
    float p = m0 * ffn_w[2 * lane] + m1 * ffn_w[2 * lane + 1];
#pragma unroll
    for (int off = 32; off > 0; off >>= 1) p += __shfl_down(p, off);
    if (lane == 0) out[mol] = p + ffn_b[0];
}

extern "C" void kernel_launch(void* const* d_in, const int* in_sizes, int n_in,
                              void* d_out, int out_size, void* d_ws, size_t ws_size,
                              hipStream_t stream) {
    const float* f_atoms = (const float*)d_in[0];
    const float* f_bonds = (const float*)d_in[1];
    const float* Wi_w = (const float*)d_in[2];
    const float* Wi_b = (const float*)d_in[3];
    const float* Wh_w = (const float*)d_in[4];
    const float* Wh_b = (const float*)d_in[5];
    const float* Wo_w = (const float*)d_in[6];
    const float* Wo_b = (const float*)d_in[7];
    const float* ffn_w = (const float*)d_in[8];
    const float* ffn_b = (const float*)d_in[9];
    const int* a2a = (const int*)d_in[10];
    const int* a2b = (const int*)d_in[11];
    float* out = (float*)d_out;

    char* ws = (char*)d_ws;
    u16* fa    = (u16*)(ws);                  // 160,000,000
    u16* xb    = (u16*)(ws + 160000000L);     // 128,000,000  (pre-relu x)
    u16* msgA  = (u16*)(ws + 288000000L);     // 128,000,000
    u16* msgB  = (u16*)(ws + 416000000L);     // 128,000,000
    u16* nsum  = (u16*)(ws + 544000000L);     // 128,000,000
    u16* nbond = (u16*)(ws + 672000000L);     // 32,000,000
    u16* Wip   = (u16*)(ws + 704000000L);     // 40960
    u16* Whp   = (u16*)(ws + 704040960L);     // 40960
    u16* Wop   = (u16*)(ws + 704081920L);     // 73728

    prep_weights<<<64, 256, 0, stream>>>(Wi_w, Wh_w, Wo_w, Wip, Whp, Wop);
    bond_gather<<<31250, 256, 0, stream>>>(f_bonds, a2b, nbond);

    // x = f_atoms @ Wi^T + b (pre-relu); also emits padded bf16 fa
    gemm_wi<<<1024, 256, 0, stream>>>(f_atoms, Wip, Wi_b, fa, xb);

    // depth 1
    gather_relu_sum<<<31250, 256, 0, stream>>>(xb, a2a, nsum);
    gemm_tlp<4, 1, true, true><<<1024, 256, 0, stream>>>(
        nsum, 128, nbond, 32, Whp, Wh_b, xb, msgA);
    // depth 2
    gather_relu_sum<<<31250, 256, 0, stream>>>(msgA, a2a, nsum);
    gemm_tlp<4, 1, true, true><<<1024, 256, 0, stream>>>(
        nsum, 128, nbond, 32, Whp, Wh_b, xb, msgB);
    // final: [fa | gather(relu(msgB))] @ Wo^T -> atom_hiddens (pre-relu) into msgA
    gather_relu_sum<<<31250, 256, 0, stream>>>(msgB, a2a, nsum);
    gemm_tlp<5, 4, false, true><<<1024, 256, 0, stream>>>(
        fa, 160, nsum, 128, Wop, Wo_b, (const u16*)nullptr, msgA);

    readout<<<6250, 256, 0, stream>>>(msgA, ffn_w, ffn_b, out);
}

// Round 11
// 1067.716 us; speedup vs baseline: 1.3990x; 1.3990x over previous
//
#include <hip/hip_runtime.h>
#include <hip/hip_bf16.h>

#define N_ATOMS   500000
#define N_BONDS   1000000
#define MAX_NB    6
#define ATOM_FDIM 133
#define BOND_FDIM 14
#define HIDDEN    128
#define N_MOLS    25000
#define APM       20

typedef __attribute__((ext_vector_type(8))) short short8;
typedef __attribute__((ext_vector_type(4))) float f32x4;
typedef unsigned short u16;
typedef unsigned int   u32;

__device__ __forceinline__ float bf2f(u16 u) {
    u32 t = ((u32)u) << 16;
    return __builtin_bit_cast(float, t);
}
__device__ __forceinline__ u16 f2bf(float f) {
    u32 t = __builtin_bit_cast(u32, f);
    t += 0x7FFFu + ((t >> 16) & 1u);
    return (u16)(t >> 16);
}
__device__ __forceinline__ u32 pk2(float a, float b) {
    return (u32)f2bf(a) | ((u32)f2bf(b) << 16);
}

// async global->LDS, 16B per lane (W staging only).
__device__ __forceinline__ void gl16(const u16* g, u16* l) {
    __builtin_amdgcn_global_load_lds(
        (__attribute__((address_space(1))) void*)(g),
        (__attribute__((address_space(3))) void*)(l), 16, 0, 0);
}

// ---------------- weight prep: fp32 -> padded bf16 ----------------
__global__ void prep_weights(const float* __restrict__ Wi, const float* __restrict__ Wh,
                             const float* __restrict__ Wo,
                             u16* __restrict__ Wip, u16* __restrict__ Whp, u16* __restrict__ Wop) {
    int stride = gridDim.x * blockDim.x;
    int tid = blockIdx.x * blockDim.x + threadIdx.x;
    for (int i = tid; i < 128 * 160; i += stride) {
        int r = i / 160, c = i % 160;
        Wip[i] = (c < 133) ? f2bf(Wi[r * 133 + c]) : (u16)0;
        Whp[i] = (c < 142) ? f2bf(Wh[r * 142 + c]) : (u16)0;
    }
    for (int i = tid; i < 128 * 288; i += stride) {
        int r = i / 288, c = i % 288;
        float v = 0.f;
        if (c < 133)      v = Wo[r * 261 + c];
        else if (c >= 160) v = Wo[r * 261 + (c - 27)];
        Wop[i] = f2bf(v);
    }
}

// ---------------- bond pre-sum: sum_j f_bonds[a2b[:,j]] -> bf16 [N][32] ----------------
__global__ __launch_bounds__(256) void bond_gather(const float* __restrict__ fb, const int* __restrict__ a2b,
                                                   u16* __restrict__ outp) {
    long t = (long)blockIdx.x * 256 + threadIdx.x;
    int atom = (int)(t >> 4);
    int c2   = (int)(t & 15);
    if (atom >= N_ATOMS) return;
    int c0 = 2 * c2, c1 = c0 + 1;
    float s0 = 0.f, s1 = 0.f;
    if (c0 < BOND_FDIM) {
#pragma unroll
        for (int j = 0; j < MAX_NB; j++) {
            int idx = a2b[atom * 6 + j];
            const float* row = fb + (long)idx * BOND_FDIM;
            s0 += row[c0];
            if (c1 < BOND_FDIM) s1 += row[c1];
        }
    }
    *(u32*)(outp + (long)atom * 32 + c0) = pk2(s0, s1);
}

// ---------------- gather-relu-sum: dst[a] = sum_j relu(src[a2a[a,j]]) (bf16 128-wide) ---
__global__ __launch_bounds__(256) void gather_relu_sum(const u16* __restrict__ src,
                                                       const int* __restrict__ a2a,
                                                       u16* __restrict__ dst) {
    long t = (long)blockIdx.x * 256 + threadIdx.x;
    int atom = (int)(t >> 4);
    int c8   = (int)(t & 15) << 3;
    float s[8] = {0, 0, 0, 0, 0, 0, 0, 0};
#pragma unroll
    for (int j = 0; j < MAX_NB; j++) {
        int idx = a2a[atom * 6 + j];
        uint4 v = *(const uint4*)(src + (long)idx * 128 + c8);
        u32 w[4] = {v.x, v.y, v.z, v.w};
#pragma unroll
        for (int q = 0; q < 4; q++) {
            s[2 * q]     += fmaxf(__builtin_bit_cast(float, w[q] << 16), 0.f);
            s[2 * q + 1] += fmaxf(__builtin_bit_cast(float, w[q] & 0xFFFF0000u), 0.f);
        }
    }
    uint4 o;
    o.x = pk2(s[0], s[1]);
    o.y = pk2(s[2], s[3]);
    o.z = pk2(s[4], s[5]);
    o.w = pk2(s[6], s[7]);
    *(uint4*)(dst + (long)atom * 128 + c8) = o;
}

// ---------------- persistent register-pipelined GEMM (r9 structure, higher occupancy) --
// Block = WAVES waves covering WAVES*16 CONTIGUOUS rows per tile (write compactness —
// r10 showed decoupled 16-row waves trigger RFO/line-bounce: FETCH 2.5x, WRITE 1.5x).
// Occupancy: KB=5 shapes run 2 blocks/CU (grid 512, VGPR capped 128 via MINW=4);
// KB=9 Wo runs 12-wave blocks (1/CU, 12 waves). DEPTH=2 register pipeline.
#define ISSUE_SLOT(d, t)                                                              \
    do {                                                                              \
        long r_ = (t) * TILE + wave * 16 + lrow;                                      \
        if (r_ > N_ATOMS - 1) r_ = N_ATOMS - 1;                                       \
        if constexpr (KB0 > 0) {                                                      \
            const u16* p_ = A0 + r_ * (long)ldA0 + kg * 8;                            \
            _Pragma("unroll") for (int kb = 0; kb < KB0; kb++)                        \
                a[d][kb] = *(const uint4*)(p_ + kb * 32);                             \
        }                                                                             \
        if constexpr (KB1 > 0) {                                                      \
            const u16* p_ = A1 + r_ * (long)ldA1 + kg * 8;                            \
            _Pragma("unroll") for (int kb = 0; kb < KB1; kb++)                        \
                a[d][KB0 + kb] = *(const uint4*)(p_ + kb * 32);                       \
        }                                                                             \
        if constexpr (ADDX) {                                                         \
            _Pragma("unroll") for (int n = 0; n < 8; n++)                             \
                xv[d][n] = *(const uint2*)(Xadd + r_ * 128 + n * 16 + kg * 4);        \
        }                                                                             \
    } while (0)

template <int KB0, int KB1, bool ADDX, bool BIAS, int DEPTH, int WAVES, int MINW>
__global__ __launch_bounds__(WAVES * 64, MINW) void gemm_rp(
    const u16* __restrict__ A0, int ldA0,
    const u16* __restrict__ A1, int ldA1,
    const u16* __restrict__ Wp, const float* __restrict__ bias,
    const u16* __restrict__ Xadd, u16* __restrict__ Out) {
    constexpr int KB    = KB0 + KB1;
    constexpr int KP    = KB * 32;
    constexpr int TILE  = WAVES * 16;
    constexpr long NT   = (N_ATOMS + TILE - 1) / TILE;
    constexpr int WSLOTS = KB * 8;
    constexpr int NWAIT = (DEPTH - 1) * (KB + 8 + (ADDX ? 8 : 0));
    static_assert(NWAIT <= 63, "vmcnt range");
    __shared__ __align__(16) u16 WL[WSLOTS * 512];

    const int lane = threadIdx.x & 63;
    const int wave = threadIdx.x >> 6;
    const int lrow = lane & 15;
    const int kg   = lane >> 4;

    for (int s = wave; s < WSLOTS; s += WAVES) {
        int kb = s >> 3, n = s & 7;
        gl16(Wp + (n * 16 + lrow) * KP + kb * 32 + kg * 8, WL + s * 512);
    }
    asm volatile("s_waitcnt vmcnt(0)" ::: "memory");
    __syncthreads();

    float4 b4[8];
#pragma unroll
    for (int n = 0; n < 8; n++)
        b4[n] = BIAS ? *(const float4*)(bias + n * 16 + kg * 4) : (float4){0.f, 0.f, 0.f, 0.f};

    const int G  = gridDim.x;
    const long t0 = blockIdx.x;

    uint4 a[DEPTH][KB];
    uint2 xv[DEPTH][ADDX ? 8 : 1];

#pragma unroll
    for (int d = 0; d < DEPTH; d++) ISSUE_SLOT(d, t0 + (long)d * G);
    __builtin_amdgcn_sched_barrier(0);

#pragma unroll 1
    for (long tt = t0; tt < NT; tt += (long)DEPTH * G) {
#pragma unroll
        for (int d = 0; d < DEPTH; d++) {
            long t = tt + (long)d * G;
            if (t < NT) {
                asm volatile("s_waitcnt vmcnt(%0)" :: "n"(NWAIT) : "memory");
                __builtin_amdgcn_sched_barrier(0);

                f32x4 acc[8];
#pragma unroll
                for (int n = 0; n < 8; n++) acc[n] = (f32x4){0.f, 0.f, 0.f, 0.f};
#pragma unroll
                for (int kb = 0; kb < KB; kb++) {
                    short8 af = __builtin_bit_cast(short8, a[d][kb]);
#pragma unroll
                    for (int n = 0; n < 8; n++) {
                        short8 bf = *(const short8*)(WL + (kb * 8 + n) * 512 + lane * 8);
                        acc[n] = __builtin_amdgcn_mfma_f32_16x16x32_bf16(bf, af, acc[n], 0, 0, 0);
                    }
                }

                long r = t * TILE + wave * 16 + lrow;
                if (r < N_ATOMS) {
#pragma unroll
                    for (int n = 0; n < 8; n++) {
                        float v0 = acc[n][0] + b4[n].x;
                        float v1 = acc[n][1] + b4[n].y;
                        float v2 = acc[n][2] + b4[n].z;
                        float v3 = acc[n][3] + b4[n].w;
                        if constexpr (ADDX) {
                            v0 += __builtin_bit_cast(float, xv[d][n].x << 16);
                            v1 += __builtin_bit_cast(float, xv[d][n].x & 0xFFFF0000u);
                            v2 += __builtin_bit_cast(float, xv[d][n].y << 16);
                            v3 += __builtin_bit_cast(float, xv[d][n].y & 0xFFFF0000u);
                        }
                        uint2 o;
                        o.x = pk2(v0, v1);
                        o.y = pk2(v2, v3);
                        *(uint2*)(Out + r * 128 + n * 16 + kg * 4) = o;
                    }
                }
                __builtin_amdgcn_sched_barrier(0);
                ISSUE_SLOT(d, t + (long)DEPTH * G);
                __builtin_amdgcn_sched_barrier(0);
            }
        }
    }
}

// ---------------- fused Wi GEMM + fa conversion (r9 structure, 2 blocks/CU) ----------
__global__ __launch_bounds__(512, 4) void gemm_wi(
    const float* __restrict__ FA, const u16* __restrict__ Wp,
    const float* __restrict__ bias, u16* __restrict__ fa16, u16* __restrict__ Out) {
    constexpr int KB = 5, KP = 160, TILE = 128;
    constexpr long NT = (N_ATOMS + TILE - 1) / TILE;
    constexpr int WSLOTS = KB * 8;
    constexpr int DEPTH = 2;
    constexpr int NWAIT = 23;  // per tile: 10 loads + 13 stores
    __shared__ __align__(16) u16 WL[WSLOTS * 512];

    const int lane = threadIdx.x & 63;
    const int wave = threadIdx.x >> 6;
    const int lrow = lane & 15;
    const int kg   = lane >> 4;

    for (int s = wave; s < WSLOTS; s += 8) {
        int kb = s >> 3, n = s & 7;
        gl16(Wp + (n * 16 + lrow) * KP + kb * 32 + kg * 8, WL + s * 512);
    }
    asm volatile("s_waitcnt vmcnt(0)" ::: "memory");
    __syncthreads();

    float4 b4[8];
#pragma unroll
    for (int n = 0; n < 8; n++) b4[n] = *(const float4*)(bias + n * 16 + kg * 4);

    const int G  = gridDim.x;
    const long t0 = blockIdx.x;

    uint4 af32[DEPTH][4][2];
    uint4 a4[DEPTH];
    float a4s[DEPTH];

#define WI_ISSUE(d, t)                                                         \
    do {                                                                       \
        long r_ = (t) * TILE + wave * 16 + lrow;                               \
        if (r_ > N_ATOMS - 1) r_ = N_ATOMS - 1;                                \
        const float* p_ = FA + r_ * (long)ATOM_FDIM + kg * 8;                  \
        _Pragma("unroll") for (int kb = 0; kb < 4; kb++) {                     \
            af32[d][kb][0] = *(const uint4*)(p_ + kb * 32);                    \
            af32[d][kb][1] = *(const uint4*)(p_ + kb * 32 + 4);                \
        }                                                                      \
        if (kg == 0) {                                                         \
            const float* q_ = FA + r_ * (long)ATOM_FDIM + 128;                 \
            a4[d]  = *(const uint4*)(q_);                                      \
            a4s[d] = q_[4];                                                    \
        }                                                                      \
    } while (0)

#pragma unroll
    for (int d = 0; d < DEPTH; d++) WI_ISSUE(d, t0 + (long)d * G);
    __builtin_amdgcn_sched_barrier(0);

#pragma unroll 1
    for (long tt = t0; tt < NT; tt += (long)DEPTH * G) {
#pragma unroll
        for (int d = 0; d < DEPTH; d++) {
            long t = tt + (long)d * G;
            if (t < NT) {
                asm volatile("s_waitcnt vmcnt(%0)" :: "n"(NWAIT) : "memory");
                __builtin_amdgcn_sched_barrier(0);

                long r = t * TILE + wave * 16 + lrow;
                bool wr = (r < N_ATOMS);

                short8 frag[5];
#pragma unroll
                for (int kb = 0; kb < 4; kb++) {
                    float4 lo = __builtin_bit_cast(float4, af32[d][kb][0]);
                    float4 hi = __builtin_bit_cast(float4, af32[d][kb][1]);
                    uint4 pk;
                    pk.x = pk2(lo.x, lo.y);
                    pk.y = pk2(lo.z, lo.w);
                    pk.z = pk2(hi.x, hi.y);
                    pk.w = pk2(hi.z, hi.w);
                    frag[kb] = __builtin_bit_cast(short8, pk);
                }
                {
                    uint4 pk = (uint4){0, 0, 0, 0};
                    if (kg == 0) {
                        float4 q = __builtin_bit_cast(float4, a4[d]);
                        pk.x = pk2(q.x, q.y);
                        pk.y = pk2(q.z, q.w);
                        pk.z = pk2(a4s[d], 0.f);
                    }
                    frag[4] = __builtin_bit_cast(short8, pk);
                }

                f32x4 acc[8];
#pragma unroll
                for (int n = 0; n < 8; n++) acc[n] = (f32x4){0.f, 0.f, 0.f, 0.f};
#pragma unroll
                for (int kb = 0; kb < 5; kb++) {
#pragma unroll
                    for (int n = 0; n < 8; n++) {
                        short8 bf = *(const short8*)(WL + (kb * 8 + n) * 512 + lane * 8);
                        acc[n] = __builtin_amdgcn_mfma_f32_16x16x32_bf16(bf, frag[kb], acc[n], 0, 0, 0);
                    }
                }

                if (wr) {
#pragma unroll
                    for (int kb = 0; kb < 5; kb++)
                        *(uint4*)(fa16 + r * 160 + kb * 32 + kg * 8) = __builtin_bit_cast(uint4, frag[kb]);
#pragma unroll
                    for (int n = 0; n < 8; n++) {
                        uint2 o;
                        o.x = pk2(acc[n][0] + b4[n].x, acc[n][1] + b4[n].y);
                        o.y = pk2(acc[n][2] + b4[n].z, acc[n][3] + b4[n].w);
                        *(uint2*)(Out + r * 128 + n * 16 + kg * 4) = o;
                    }
                }
                __builtin_amdgcn_sched_barrier(0);
                WI_ISSUE(d, t + (long)DEPTH * G);
                __builtin_amdgcn_sched_barrier(0);
            }
        }
    }
#undef WI_ISSUE
}

// ---------------- readout: per-mol max over 20 atoms (w/ relu) then dot ffn_w ----------
__global__ __launch_bounds__(256) void readout(const u16* __restrict__ ah,
                                               const float* __restrict__ ffn_w,
                                               const float* __restrict__ ffn_b,
                                               float* __restrict__ out) {
    int mol  = blockIdx.x * 4 + (threadIdx.x >> 6);
    int lane = threadIdx.x & 63;
    if (mol >= N_MOLS) return;
    float m0 = -1e30f, m1 = -1e30f;
    const u16* base = ah + (long)mol * APM * 128 + 2 * lane;
#pragma unroll
    for (int a = 0; a < APM; a++) {
        u32 v = *(const u32*)(base + a * 128);
        m0 = fmaxf(m0, bf2f((u16)(v & 0xFFFFu)));
        m1 = fmaxf(m1, bf2f((u16)(v >> 16)));
    }
    m0 = fmaxf(m0, 0.f);
    m1 = fmaxf(m1, 0.f);
    float p = m0 * ffn_w[2 * lane] + m1 * ffn_w[2 * lane + 1];
#pragma unroll
    for (int off = 32; off > 0; off >>= 1) p += __shfl_down(p, off);
    if (lane == 0) out[mol] = p + ffn_b[0];
}

extern "C" void kernel_launch(void* const* d_in, const int* in_sizes, int n_in,
                              void* d_out, int out_size, void* d_ws, size_t ws_size,
                              hipStream_t stream) {
    const float* f_atoms = (const float*)d_in[0];
    const float* f_bonds = (const float*)d_in[1];
    const float* Wi_w = (const float*)d_in[2];
    const float* Wi_b = (const float*)d_in[3];
    const float* Wh_w = (const float*)d_in[4];
    const float* Wh_b = (const float*)d_in[5];
    const float* Wo_w = (const float*)d_in[6];
    const float* Wo_b = (const float*)d_in[7];
    const float* ffn_w = (const float*)d_in[8];
    const float* ffn_b = (const float*)d_in[9];
    const int* a2a = (const int*)d_in[10];
    const int* a2b = (const int*)d_in[11];
    float* out = (float*)d_out;

    char* ws = (char*)d_ws;
    u16* fa    = (u16*)(ws);                  // 160,000,000
    u16* xb    = (u16*)(ws + 160000000L);     // 128,000,000  (pre-relu x)
    u16* msgA  = (u16*)(ws + 288000000L);     // 128,000,000
    u16* msgB  = (u16*)(ws + 416000000L);     // 128,000,000
    u16* nsum  = (u16*)(ws + 544000000L);     // 128,000,000
    u16* nbond = (u16*)(ws + 672000000L);     // 32,000,000
    u16* Wip   = (u16*)(ws + 704000000L);     // 40960
    u16* Whp   = (u16*)(ws + 704040960L);     // 40960
    u16* Wop   = (u16*)(ws + 704081920L);     // 73728

    prep_weights<<<64, 256, 0, stream>>>(Wi_w, Wh_w, Wo_w, Wip, Whp, Wop);
    bond_gather<<<31250, 256, 0, stream>>>(f_bonds, a2b, nbond);

    // x = f_atoms @ Wi^T + b (pre-relu); also emits padded bf16 fa. 2 blocks/CU.
    gemm_wi<<<512, 512, 0, stream>>>(f_atoms, Wip, Wi_b, fa, xb);

    // depth 1 (2 blocks/CU, 16 waves/CU)
    gather_relu_sum<<<31250, 256, 0, stream>>>(xb, a2a, nsum);
    gemm_rp<4, 1, true, true, 2, 8, 4><<<512, 512, 0, stream>>>(
        nsum, 128, nbond, 32, Whp, Wh_b, xb, msgA);
    // depth 2
    gather_relu_sum<<<31250, 256, 0, stream>>>(msgA, a2a, nsum);
    gemm_rp<4, 1, true, true, 2, 8, 4><<<512, 512, 0, stream>>>(
        nsum, 128, nbond, 32, Whp, Wh_b, xb, msgB);
    // final: [fa | gather(relu(msgB))] @ Wo^T -> atom_hiddens (pre-relu) into msgA
    // 12-wave blocks (192 contiguous rows), 1 block/CU, 12 waves/CU.
    gather_relu_sum<<<31250, 256, 0, stream>>>(msgB, a2a, nsum);
    gemm_rp<5, 4, false, true, 2, 12, 3><<<256, 768, 0, stream>>>(
        fa, 160, nsum, 128, Wop, Wo_b, (const u16*)nullptr, msgA);

    readout<<<6250, 256, 0, stream>>>(msgA, ffn_w, ffn_b, out);
}

// Round 12
// 921.571 us; speedup vs baseline: 1.6209x; 1.1586x over previous
//
#include <hip/hip_runtime.h>
#include <hip/hip_bf16.h>

#define N_ATOMS   500000
#define N_BONDS   1000000
#define MAX_NB    6
#define ATOM_FDIM 133
#define BOND_FDIM 14
#define HIDDEN    128
#define N_MOLS    25000
#define APM       20

typedef __attribute__((ext_vector_type(8))) short short8;
typedef __attribute__((ext_vector_type(4))) float f32x4;
typedef __attribute__((ext_vector_type(4))) unsigned int u32x4;
typedef __attribute__((ext_vector_type(2))) unsigned int u32x2;
typedef unsigned short u16;
typedef unsigned int   u32;

__device__ __forceinline__ float bf2f(u16 u) {
    u32 t = ((u32)u) << 16;
    return __builtin_bit_cast(float, t);
}
__device__ __forceinline__ u16 f2bf(float f) {
    u32 t = __builtin_bit_cast(u32, f);
    t += 0x7FFFu + ((t >> 16) & 1u);
    return (u16)(t >> 16);
}
__device__ __forceinline__ u32 pk2(float a, float b) {
    return (u32)f2bf(a) | ((u32)f2bf(b) << 16);
}

template <bool NTH, typename T>
__device__ __forceinline__ T ldh(const T* p) {
    if constexpr (NTH) return __builtin_nontemporal_load(p);
    else               return *p;
}
template <bool NTH, typename T>
__device__ __forceinline__ void sth(T* p, T v) {
    if constexpr (NTH) __builtin_nontemporal_store(v, p);
    else               *p = v;
}

// async global->LDS, 16B per lane (W staging only).
__device__ __forceinline__ void gl16(const u16* g, u16* l) {
    __builtin_amdgcn_global_load_lds(
        (__attribute__((address_space(1))) void*)(g),
        (__attribute__((address_space(3))) void*)(l), 16, 0, 0);
}

// ---------------- weight prep: fp32 -> padded bf16 ----------------
__global__ void prep_weights(const float* __restrict__ Wi, const float* __restrict__ Wh,
                             const float* __restrict__ Wo,
                             u16* __restrict__ Wip, u16* __restrict__ Whp, u16* __restrict__ Wop) {
    int stride = gridDim.x * blockDim.x;
    int tid = blockIdx.x * blockDim.x + threadIdx.x;
    for (int i = tid; i < 128 * 160; i += stride) {
        int r = i / 160, c = i % 160;
        Wip[i] = (c < 133) ? f2bf(Wi[r * 133 + c]) : (u16)0;
        Whp[i] = (c < 142) ? f2bf(Wh[r * 142 + c]) : (u16)0;
    }
    for (int i = tid; i < 128 * 288; i += stride) {
        int r = i / 288, c = i % 288;
        float v = 0.f;
        if (c < 133)      v = Wo[r * 261 + c];
        else if (c >= 160) v = Wo[r * 261 + (c - 27)];
        Wop[i] = f2bf(v);
    }
}

// ---------------- bond pre-sum: sum_j f_bonds[a2b[:,j]] -> bf16 [N][32] ----------------
__global__ __launch_bounds__(256) void bond_gather(const float* __restrict__ fb, const int* __restrict__ a2b,
                                                   u16* __restrict__ outp) {
    long t = (long)blockIdx.x * 256 + threadIdx.x;
    int atom = (int)(t >> 4);
    int c2   = (int)(t & 15);
    if (atom >= N_ATOMS) return;
    int c0 = 2 * c2, c1 = c0 + 1;
    float s0 = 0.f, s1 = 0.f;
    if (c0 < BOND_FDIM) {
#pragma unroll
        for (int j = 0; j < MAX_NB; j++) {
            int idx = a2b[atom * 6 + j];
            const float* row = fb + (long)idx * BOND_FDIM;
            s0 += row[c0];
            if (c1 < BOND_FDIM) s1 += row[c1];
        }
    }
    *(u32*)(outp + (long)atom * 32 + c0) = pk2(s0, s1);
}

// ---------------- gather-relu-sum: dst[a] = sum_j relu(src[a2a[a,j]]) (bf16 128-wide) ---
__global__ __launch_bounds__(256) void gather_relu_sum(const u16* __restrict__ src,
                                                       const int* __restrict__ a2a,
                                                       u16* __restrict__ dst) {
    long t = (long)blockIdx.x * 256 + threadIdx.x;
    int atom = (int)(t >> 4);
    int c8   = (int)(t & 15) << 3;
    float s[8] = {0, 0, 0, 0, 0, 0, 0, 0};
#pragma unroll
    for (int j = 0; j < MAX_NB; j++) {
        int idx = a2a[atom * 6 + j];
        uint4 v = *(const uint4*)(src + (long)idx * 128 + c8);
        u32 w[4] = {v.x, v.y, v.z, v.w};
#pragma unroll
        for (int q = 0; q < 4; q++) {
            s[2 * q]     += fmaxf(__builtin_bit_cast(float, w[q] << 16), 0.f);
            s[2 * q + 1] += fmaxf(__builtin_bit_cast(float, w[q] & 0xFFFF0000u), 0.f);
        }
    }
    uint4 o;
    o.x = pk2(s[0], s[1]);
    o.y = pk2(s[2], s[3]);
    o.z = pk2(s[4], s[5]);
    o.w = pk2(s[6], s[7]);
    *(uint4*)(dst + (long)atom * 128 + c8) = o;
}

// ---------------- persistent register-pipelined GEMM (r8 = 873us structure) ----------
// NTH template: non-temporal hints on once-touched streams (A loads, Xadd loads, Out
// stores) -- within-run A/B: depth-1 Wh runs NTH=false, depth-2 Wh runs NTH=true.
#define ISSUE_SLOT(d, t)                                                              \
    do {                                                                              \
        long r_ = (t) * TILE + wave * 16 + lrow;                                      \
        if (r_ > N_ATOMS - 1) r_ = N_ATOMS - 1;                                       \
        if constexpr (KB0 > 0) {                                                      \
            const u16* p_ = A0 + r_ * (long)ldA0 + kg * 8;                            \
            _Pragma("unroll") for (int kb = 0; kb < KB0; kb++)                        \
                a[d][kb] = ldh<NTH>((const u32x4*)(p_ + kb * 32));                    \
        }                                                                             \
        if constexpr (KB1 > 0) {                                                      \
            const u16* p_ = A1 + r_ * (long)ldA1 + kg * 8;                            \
            _Pragma("unroll") for (int kb = 0; kb < KB1; kb++)                        \
                a[d][KB0 + kb] = ldh<NTH>((const u32x4*)(p_ + kb * 32));              \
        }                                                                             \
        if constexpr (ADDX) {                                                         \
            _Pragma("unroll") for (int n = 0; n < 8; n++)                             \
                xv[d][n] = ldh<NTH>((const u32x2*)(Xadd + r_ * 128 + n * 16 + kg * 4)); \
        }                                                                             \
    } while (0)

template <int KB0, int KB1, bool ADDX, bool BIAS, int DEPTH, bool NTH>
__global__ __launch_bounds__(512, 2) void gemm_rp(
    const u16* __restrict__ A0, int ldA0,
    const u16* __restrict__ A1, int ldA1,
    const u16* __restrict__ Wp, const float* __restrict__ bias,
    const u16* __restrict__ Xadd, u16* __restrict__ Out) {
    constexpr int KB    = KB0 + KB1;
    constexpr int KP    = KB * 32;
    constexpr int TILE  = 128;
    constexpr long NT   = (N_ATOMS + TILE - 1) / TILE;
    constexpr int WSLOTS = KB * 8;
    constexpr int NWAIT = (DEPTH - 1) * (KB + 8 + (ADDX ? 8 : 0));
    static_assert(NWAIT <= 63, "vmcnt range");
    __shared__ __align__(16) u16 WL[WSLOTS * 512];

    const int lane = threadIdx.x & 63;
    const int wave = threadIdx.x >> 6;
    const int lrow = lane & 15;
    const int kg   = lane >> 4;

    for (int s = wave; s < WSLOTS; s += 8) {
        int kb = s >> 3, n = s & 7;
        gl16(Wp + (n * 16 + lrow) * KP + kb * 32 + kg * 8, WL + s * 512);
    }
    asm volatile("s_waitcnt vmcnt(0)" ::: "memory");
    __syncthreads();

    float4 b4[8];
#pragma unroll
    for (int n = 0; n < 8; n++)
        b4[n] = BIAS ? *(const float4*)(bias + n * 16 + kg * 4) : (float4){0.f, 0.f, 0.f, 0.f};

    const int G  = gridDim.x;
    const long t0 = blockIdx.x;

    u32x4 a[DEPTH][KB];
    u32x2 xv[DEPTH][ADDX ? 8 : 1];

#pragma unroll
    for (int d = 0; d < DEPTH; d++) ISSUE_SLOT(d, t0 + (long)d * G);
    __builtin_amdgcn_sched_barrier(0);

#pragma unroll 1
    for (long tt = t0; tt < NT; tt += (long)DEPTH * G) {
#pragma unroll
        for (int d = 0; d < DEPTH; d++) {
            long t = tt + (long)d * G;
            if (t < NT) {
                asm volatile("s_waitcnt vmcnt(%0)" :: "n"(NWAIT) : "memory");
                __builtin_amdgcn_sched_barrier(0);

                f32x4 acc[8];
#pragma unroll
                for (int n = 0; n < 8; n++) acc[n] = (f32x4){0.f, 0.f, 0.f, 0.f};
#pragma unroll
                for (int kb = 0; kb < KB; kb++) {
                    short8 af = __builtin_bit_cast(short8, a[d][kb]);
#pragma unroll
                    for (int n = 0; n < 8; n++) {
                        short8 bf = *(const short8*)(WL + (kb * 8 + n) * 512 + lane * 8);
                        acc[n] = __builtin_amdgcn_mfma_f32_16x16x32_bf16(bf, af, acc[n], 0, 0, 0);
                    }
                }

                long r = t * TILE + wave * 16 + lrow;
                if (r < N_ATOMS) {
#pragma unroll
                    for (int n = 0; n < 8; n++) {
                        float v0 = acc[n][0] + b4[n].x;
                        float v1 = acc[n][1] + b4[n].y;
                        float v2 = acc[n][2] + b4[n].z;
                        float v3 = acc[n][3] + b4[n].w;
                        if constexpr (ADDX) {
                            v0 += __builtin_bit_cast(float, xv[d][n].x << 16);
                            v1 += __builtin_bit_cast(float, xv[d][n].x & 0xFFFF0000u);
                            v2 += __builtin_bit_cast(float, xv[d][n].y << 16);
                            v3 += __builtin_bit_cast(float, xv[d][n].y & 0xFFFF0000u);
                        }
                        u32x2 o;
                        o.x = pk2(v0, v1);
                        o.y = pk2(v2, v3);
                        sth<NTH>((u32x2*)(Out + r * 128 + n * 16 + kg * 4), o);
                    }
                }
                __builtin_amdgcn_sched_barrier(0);
                ISSUE_SLOT(d, t + (long)DEPTH * G);
                __builtin_amdgcn_sched_barrier(0);
            }
        }
    }
}

// ---------------- fused Wi GEMM + fa conversion (r8 exact) ----------
__global__ __launch_bounds__(512, 2) void gemm_wi(
    const float* __restrict__ FA, const u16* __restrict__ Wp,
    const float* __restrict__ bias, u16* __restrict__ fa16, u16* __restrict__ Out) {
    constexpr int KB = 5, KP = 160, TILE = 128;
    constexpr long NT = (N_ATOMS + TILE - 1) / TILE;
    constexpr int WSLOTS = KB * 8;
    constexpr int DEPTH = 2;
    constexpr int NWAIT = 23;
    __shared__ __align__(16) u16 WL[WSLOTS * 512];

    const int lane = threadIdx.x & 63;
    const int wave = threadIdx.x >> 6;
    const int lrow = lane & 15;
    const int kg   = lane >> 4;

    for (int s = wave; s < WSLOTS; s += 8) {
        int kb = s >> 3, n = s & 7;
        gl16(Wp + (n * 16 + lrow) * KP + kb * 32 + kg * 8, WL + s * 512);
    }
    asm volatile("s_waitcnt vmcnt(0)" ::: "memory");
    __syncthreads();

    float4 b4[8];
#pragma unroll
    for (int n = 0; n < 8; n++) b4[n] = *(const float4*)(bias + n * 16 + kg * 4);

    const int G  = gridDim.x;
    const long t0 = blockIdx.x;

    uint4 af32[DEPTH][4][2];
    uint4 a4[DEPTH];
    float a4s[DEPTH];

#define WI_ISSUE(d, t)                                                         \
    do {                                                                       \
        long r_ = (t) * TILE + wave * 16 + lrow;                               \
        if (r_ > N_ATOMS - 1) r_ = N_ATOMS - 1;                                \
        const float* p_ = FA + r_ * (long)ATOM_FDIM + kg * 8;                  \
        _Pragma("unroll") for (int kb = 0; kb < 4; kb++) {                     \
            af32[d][kb][0] = *(const uint4*)(p_ + kb * 32);                    \
            af32[d][kb][1] = *(const uint4*)(p_ + kb * 32 + 4);                \
        }                                                                      \
        if (kg == 0) {                                                         \
            const float* q_ = FA + r_ * (long)ATOM_FDIM + 128;                 \
            a4[d]  = *(const uint4*)(q_);                                      \
            a4s[d] = q_[4];                                                    \
        }                                                                      \
    } while (0)

#pragma unroll
    for (int d = 0; d < DEPTH; d++) WI_ISSUE(d, t0 + (long)d * G);
    __builtin_amdgcn_sched_barrier(0);

#pragma unroll 1
    for (long tt = t0; tt < NT; tt += (long)DEPTH * G) {
#pragma unroll
        for (int d = 0; d < DEPTH; d++) {
            long t = tt + (long)d * G;
            if (t < NT) {
                asm volatile("s_waitcnt vmcnt(%0)" :: "n"(NWAIT) : "memory");
                __builtin_amdgcn_sched_barrier(0);

                long r = t * TILE + wave * 16 + lrow;
                bool wr = (r < N_ATOMS);

                short8 frag[5];
#pragma unroll
                for (int kb = 0; kb < 4; kb++) {
                    float4 lo = __builtin_bit_cast(float4, af32[d][kb][0]);
                    float4 hi = __builtin_bit_cast(float4, af32[d][kb][1]);
                    uint4 pk;
                    pk.x = pk2(lo.x, lo.y);
                    pk.y = pk2(lo.z, lo.w);
                    pk.z = pk2(hi.x, hi.y);
                    pk.w = pk2(hi.z, hi.w);
                    frag[kb] = __builtin_bit_cast(short8, pk);
                }
                {
                    uint4 pk = (uint4){0, 0, 0, 0};
                    if (kg == 0) {
                        float4 q = __builtin_bit_cast(float4, a4[d]);
                        pk.x = pk2(q.x, q.y);
                        pk.y = pk2(q.z, q.w);
                        pk.z = pk2(a4s[d], 0.f);
                    }
                    frag[4] = __builtin_bit_cast(short8, pk);
                }

                f32x4 acc[8];
#pragma unroll
                for (int n = 0; n < 8; n++) acc[n] = (f32x4){0.f, 0.f, 0.f, 0.f};
#pragma unroll
                for (int kb = 0; kb < 5; kb++) {
#pragma unroll
                    for (int n = 0; n < 8; n++) {
                        short8 bf = *(const short8*)(WL + (kb * 8 + n) * 512 + lane * 8);
                        acc[n] = __builtin_amdgcn_mfma_f32_16x16x32_bf16(bf, frag[kb], acc[n], 0, 0, 0);
                    }
                }

                if (wr) {
#pragma unroll
                    for (int kb = 0; kb < 5; kb++)
                        *(uint4*)(fa16 + r * 160 + kb * 32 + kg * 8) = __builtin_bit_cast(uint4, frag[kb]);
#pragma unroll
                    for (int n = 0; n < 8; n++) {
                        uint2 o;
                        o.x = pk2(acc[n][0] + b4[n].x, acc[n][1] + b4[n].y);
                        o.y = pk2(acc[n][2] + b4[n].z, acc[n][3] + b4[n].w);
                        *(uint2*)(Out + r * 128 + n * 16 + kg * 4) = o;
                    }
                }
                __builtin_amdgcn_sched_barrier(0);
                WI_ISSUE(d, t + (long)DEPTH * G);
                __builtin_amdgcn_sched_barrier(0);
            }
        }
    }
#undef WI_ISSUE
}

// ---------------- readout: per-mol max over 20 atoms (w/ relu) then dot ffn_w ----------
__global__ __launch_bounds__(256) void readout(const u16* __restrict__ ah,
                                               const float* __restrict__ ffn_w,
                                               const float* __restrict__ ffn_b,
                                               float* __restrict__ out) {
    int mol  = blockIdx.x * 4 + (threadIdx.x >> 6);
    int lane = threadIdx.x & 63;
    if (mol >= N_MOLS) return;
    float m0 = -1e30f, m1 = -1e30f;
    const u16* base = ah + (long)mol * APM * 128 + 2 * lane;
#pragma unroll
    for (int a = 0; a < APM; a++) {
        u32 v = *(const u32*)(base + a * 128);
        m0 = fmaxf(m0, bf2f((u16)(v & 0xFFFFu)));
        m1 = fmaxf(m1, bf2f((u16)(v >> 16)));
    }
    m0 = fmaxf(m0, 0.f);
    m1 = fmaxf(m1, 0.f);
    float p = m0 * ffn_w[2 * lane] + m1 * ffn_w[2 * lane + 1];
#pragma unroll
    for (int off = 32; off > 0; off >>= 1) p += __shfl_down(p, off);
    if (lane == 0) out[mol] = p + ffn_b[0];
}

extern "C" void kernel_launch(void* const* d_in, const int* in_sizes, int n_in,
                              void* d_out, int out_size, void* d_ws, size_t ws_size,
                              hipStream_t stream) {
    const float* f_atoms = (const float*)d_in[0];
    const float* f_bonds = (const float*)d_in[1];
    const float* Wi_w = (const float*)d_in[2];
    const float* Wi_b = (const float*)d_in[3];
    const float* Wh_w = (const float*)d_in[4];
    const float* Wh_b = (const float*)d_in[5];
    const float* Wo_w = (const float*)d_in[6];
    const float* Wo_b = (const float*)d_in[7];
    const float* ffn_w = (const float*)d_in[8];
    const float* ffn_b = (const float*)d_in[9];
    const int* a2a = (const int*)d_in[10];
    const int* a2b = (const int*)d_in[11];
    float* out = (float*)d_out;

    char* ws = (char*)d_ws;
    u16* fa    = (u16*)(ws);                  // 160,000,000
    u16* xb    = (u16*)(ws + 160000000L);     // 128,000,000  (pre-relu x)
    u16* msgA  = (u16*)(ws + 288000000L);     // 128,000,000
    u16* msgB  = (u16*)(ws + 416000000L);     // 128,000,000
    u16* nsum  = (u16*)(ws + 544000000L);     // 128,000,000
    u16* nbond = (u16*)(ws + 672000000L);     // 32,000,000
    u16* Wip   = (u16*)(ws + 704000000L);     // 40960
    u16* Whp   = (u16*)(ws + 704040960L);     // 40960
    u16* Wop   = (u16*)(ws + 704081920L);     // 73728

    prep_weights<<<64, 256, 0, stream>>>(Wi_w, Wh_w, Wo_w, Wip, Whp, Wop);
    bond_gather<<<31250, 256, 0, stream>>>(f_bonds, a2b, nbond);

    // x = f_atoms @ Wi^T + b (pre-relu); also emits padded bf16 fa
    gemm_wi<<<256, 512, 0, stream>>>(f_atoms, Wip, Wi_b, fa, xb);

    // depth 1 -- baseline (temporal)
    gather_relu_sum<<<31250, 256, 0, stream>>>(xb, a2a, nsum);
    gemm_rp<4, 1, true, true, 4, false><<<256, 512, 0, stream>>>(
        nsum, 128, nbond, 32, Whp, Wh_b, xb, msgA);
    // depth 2 -- A/B variant: non-temporal once-touched streams
    gather_relu_sum<<<31250, 256, 0, stream>>>(msgA, a2a, nsum);
    gemm_rp<4, 1, true, true, 4, true><<<256, 512, 0, stream>>>(
        nsum, 128, nbond, 32, Whp, Wh_b, xb, msgB);
    // final: [fa | gather(relu(msgB))] @ Wo^T -> atom_hiddens (pre-relu) into msgA
    gather_relu_sum<<<31250, 256, 0, stream>>>(msgB, a2a, nsum);
    gemm_rp<5, 4, false, true, 3, false><<<256, 512, 0, stream>>>(
        fa, 160, nsum, 128, Wop, Wo_b, (const u16*)nullptr, msgA);

    readout<<<6250, 256, 0, stream>>>(msgA, ffn_w, ffn_b, out);
}

// Round 13
// 813.891 us; speedup vs baseline: 1.8354x; 1.1323x over previous
//
#include <hip/hip_runtime.h>
#include <hip/hip_bf16.h>

#define N_ATOMS   500000
#define N_BONDS   1000000
#define MAX_NB    6
#define ATOM_FDIM 133
#define BOND_FDIM 14
#define HIDDEN    128
#define N_MOLS    25000
#define APM       20

typedef __attribute__((ext_vector_type(8))) short short8;
typedef __attribute__((ext_vector_type(4))) float f32x4;
typedef unsigned short u16;
typedef unsigned int   u32;

__device__ __forceinline__ float bf2f(u16 u) {
    u32 t = ((u32)u) << 16;
    return __builtin_bit_cast(float, t);
}
__device__ __forceinline__ u16 f2bf(float f) {
    u32 t = __builtin_bit_cast(u32, f);
    t += 0x7FFFu + ((t >> 16) & 1u);
    return (u16)(t >> 16);
}
__device__ __forceinline__ u32 pk2(float a, float b) {
    return (u32)f2bf(a) | ((u32)f2bf(b) << 16);
}

// async global->LDS, 16B per lane. LDS dest = uniform base + lane*16; global src per-lane.
__device__ __forceinline__ void gl16(const u16* g, u16* l) {
    __builtin_amdgcn_global_load_lds(
        (__attribute__((address_space(1))) void*)(g),
        (__attribute__((address_space(3))) void*)(l), 16, 0, 0);
}

// ---------------- weight prep: fp32 -> padded bf16 ----------------
__global__ void prep_weights(const float* __restrict__ Wi, const float* __restrict__ Wh,
                             const float* __restrict__ Wo,
                             u16* __restrict__ Wip, u16* __restrict__ Whp, u16* __restrict__ Wop) {
    int stride = gridDim.x * blockDim.x;
    int tid = blockIdx.x * blockDim.x + threadIdx.x;
    for (int i = tid; i < 128 * 160; i += stride) {
        int r = i / 160, c = i % 160;
        Wip[i] = (c < 133) ? f2bf(Wi[r * 133 + c]) : (u16)0;
        Whp[i] = (c < 142) ? f2bf(Wh[r * 142 + c]) : (u16)0;
    }
    for (int i = tid; i < 128 * 288; i += stride) {
        int r = i / 288, c = i % 288;
        float v = 0.f;
        if (c < 133)      v = Wo[r * 261 + c];
        else if (c >= 160) v = Wo[r * 261 + (c - 27)];
        Wop[i] = f2bf(v);
    }
}

// ---------------- bond pre-sum: sum_j f_bonds[a2b[:,j]] -> bf16 [N][32] ----------------
__global__ __launch_bounds__(256) void bond_gather(const float* __restrict__ fb, const int* __restrict__ a2b,
                                                   u16* __restrict__ outp) {
    long t = (long)blockIdx.x * 256 + threadIdx.x;
    int atom = (int)(t >> 4);
    int c2   = (int)(t & 15);
    if (atom >= N_ATOMS) return;
    int c0 = 2 * c2, c1 = c0 + 1;
    float s0 = 0.f, s1 = 0.f;
    if (c0 < BOND_FDIM) {
#pragma unroll
        for (int j = 0; j < MAX_NB; j++) {
            int idx = a2b[atom * 6 + j];
            const float* row = fb + (long)idx * BOND_FDIM;
            s0 += row[c0];
            if (c1 < BOND_FDIM) s1 += row[c1];
        }
    }
    *(u32*)(outp + (long)atom * 32 + c0) = pk2(s0, s1);
}

// ---------------- gather-relu-sum: dst[a] = sum_j relu(src[a2a[a,j]]) (bf16 128-wide) ---
__global__ __launch_bounds__(256) void gather_relu_sum(const u16* __restrict__ src,
                                                       const int* __restrict__ a2a,
                                                       u16* __restrict__ dst) {
    long t = (long)blockIdx.x * 256 + threadIdx.x;
    int atom = (int)(t >> 4);
    int c8   = (int)(t & 15) << 3;
    float s[8] = {0, 0, 0, 0, 0, 0, 0, 0};
#pragma unroll
    for (int j = 0; j < MAX_NB; j++) {
        int idx = a2a[atom * 6 + j];
        uint4 v = *(const uint4*)(src + (long)idx * 128 + c8);
        u32 w[4] = {v.x, v.y, v.z, v.w};
#pragma unroll
        for (int q = 0; q < 4; q++) {
            s[2 * q]     += fmaxf(__builtin_bit_cast(float, w[q] << 16), 0.f);
            s[2 * q + 1] += fmaxf(__builtin_bit_cast(float, w[q] & 0xFFFF0000u), 0.f);
        }
    }
    uint4 o;
    o.x = pk2(s[0], s[1]);
    o.y = pk2(s[2], s[3]);
    o.z = pk2(s[4], s[5]);
    o.w = pk2(s[6], s[7]);
    *(uint4*)(dst + (long)atom * 128 + c8) = o;
}

// ---------------- persistent DMA-pipelined GEMM with linear-store epilogue ------------
// Out = concat(A0[KB0 via global_load_lds DMA], A1[KB1 via registers]) @ Wp^T (+bias)(+Xadd)
// - A0 tiles: DMA into per-wave double-buffered LDS slots (no VGPR destinations -> the
//   register allocator cannot demote the pipeline; in-flight bytes >> Little's law).
// - Counted vmcnt (never 0 in main loop): NWAIT = KB0 DMAs + KB1+X reg loads + 4 stores.
// - Epilogue: results packed to swizzled per-wave 4KB LDS buffer, then 4x ds_read_b128 +
//   4x global_store_dwordx4 = one CONTIGUOUS 4KB block per wave (fixes r12's 2x WRITE
//   amplification from 8B scattered stores).
#define ISSUE_SLOT(d, t)                                                              \
    do {                                                                              \
        long r_ = (t) * TILE + wave * 16 + lrow;                                      \
        if (r_ > N_ATOMS - 1) r_ = N_ATOMS - 1;                                       \
        u16* ab_ = AL + ((d) * WAVES + wave) * (KB0 * 512);                           \
        {                                                                             \
            const u16* p_ = A0 + r_ * (long)ldA0 + kg * 8;                            \
            _Pragma("unroll") for (int kb = 0; kb < KB0; kb++)                        \
                gl16(p_ + kb * 32, ab_ + kb * 512);                                   \
        }                                                                             \
        if constexpr (KB1 > 0) {                                                      \
            const u16* p_ = A1 + r_ * (long)ldA1 + kg * 8;                            \
            _Pragma("unroll") for (int kb = 0; kb < KB1; kb++)                        \
                a1v[d][kb] = *(const uint4*)(p_ + kb * 32);                           \
        }                                                                             \
        if constexpr (ADDX) {                                                         \
            _Pragma("unroll") for (int n = 0; n < 8; n++)                             \
                xv[d][n] = *(const uint2*)(Xadd + r_ * 128 + n * 16 + kg * 4);        \
        }                                                                             \
    } while (0)

template <int KB0, int KB1, bool ADDX, bool BIAS, int WAVES>
__global__ __launch_bounds__(WAVES * 64) void gemm_dma(
    const u16* __restrict__ A0, int ldA0,
    const u16* __restrict__ A1, int ldA1,
    const u16* __restrict__ Wp, const float* __restrict__ bias,
    const u16* __restrict__ Xadd, u16* __restrict__ Out) {
    constexpr int KB    = KB0 + KB1;
    constexpr int KP    = KB * 32;
    constexpr int TILE  = WAVES * 16;
    constexpr long NT   = (N_ATOMS + TILE - 1) / TILE;
    constexpr int WSLOTS = KB * 8;
    constexpr int DEPTH = 2;
    constexpr int NWAIT = KB0 + (KB1 > 0 ? KB1 : 0) + (ADDX ? 8 : 0) + 4;
    static_assert(NWAIT <= 63, "vmcnt range");
    // LDS: W fragments | A0 DMA slots (DEPTH x WAVES x KB0 KB) | store staging (4KB/wave)
    __shared__ __align__(16) u16 lds[WSLOTS * 512 + DEPTH * WAVES * KB0 * 512 + WAVES * 2048];

    const int lane = threadIdx.x & 63;
    const int wave = threadIdx.x >> 6;
    const int lrow = lane & 15;
    const int kg   = lane >> 4;

    u16* WL = lds;
    u16* AL = lds + WSLOTS * 512;
    u16* SB = lds + WSLOTS * 512 + DEPTH * WAVES * KB0 * 512;

    for (int s = wave; s < WSLOTS; s += WAVES) {
        int kb = s >> 3, n = s & 7;
        gl16(Wp + (n * 16 + lrow) * KP + kb * 32 + kg * 8, WL + s * 512);
    }
    asm volatile("s_waitcnt vmcnt(0)" ::: "memory");
    __syncthreads();

    float4 b4[8];
#pragma unroll
    for (int n = 0; n < 8; n++)
        b4[n] = BIAS ? *(const float4*)(bias + n * 16 + kg * 4) : (float4){0.f, 0.f, 0.f, 0.f};

    const int G  = gridDim.x;
    const long t0 = blockIdx.x;

    uint4 a1v[DEPTH][KB1 > 0 ? KB1 : 1];
    uint2 xv[DEPTH][ADDX ? 8 : 1];

#pragma unroll
    for (int d = 0; d < DEPTH; d++) ISSUE_SLOT(d, t0 + (long)d * G);
    __builtin_amdgcn_sched_barrier(0);

#pragma unroll 1
    for (long tt = t0; tt < NT; tt += (long)DEPTH * G) {
#pragma unroll
        for (int d = 0; d < DEPTH; d++) {
            long t = tt + (long)d * G;
            if (t < NT) {
                asm volatile("s_waitcnt vmcnt(%0)" :: "n"(NWAIT) : "memory");
                __builtin_amdgcn_sched_barrier(0);

                const u16* ab = AL + (d * WAVES + wave) * (KB0 * 512);
                f32x4 acc[8];
#pragma unroll
                for (int n = 0; n < 8; n++) acc[n] = (f32x4){0.f, 0.f, 0.f, 0.f};
#pragma unroll
                for (int kb = 0; kb < KB; kb++) {
                    short8 af;
                    if (kb < KB0) af = *(const short8*)(ab + kb * 512 + lane * 8);
                    else          af = __builtin_bit_cast(short8, a1v[d][(kb - KB0) < KB1 ? (kb - KB0) : 0]);
#pragma unroll
                    for (int n = 0; n < 8; n++) {
                        short8 bf = *(const short8*)(WL + (kb * 8 + n) * 512 + lane * 8);
                        acc[n] = __builtin_amdgcn_mfma_f32_16x16x32_bf16(bf, af, acc[n], 0, 0, 0);
                    }
                }

                const long wrow0 = t * TILE + wave * 16;
                if (wrow0 < N_ATOMS) {  // wave-uniform (N_ATOMS % 16 == 0)
                    u16* sb = SB + wave * 2048;
#pragma unroll
                    for (int n = 0; n < 8; n++) {
                        float v0 = acc[n][0] + b4[n].x;
                        float v1 = acc[n][1] + b4[n].y;
                        float v2 = acc[n][2] + b4[n].z;
                        float v3 = acc[n][3] + b4[n].w;
                        if constexpr (ADDX) {
                            v0 += __builtin_bit_cast(float, xv[d][n].x << 16);
                            v1 += __builtin_bit_cast(float, xv[d][n].x & 0xFFFF0000u);
                            v2 += __builtin_bit_cast(float, xv[d][n].y << 16);
                            v3 += __builtin_bit_cast(float, xv[d][n].y & 0xFFFF0000u);
                        }
                        uint2 o;
                        o.x = pk2(v0, v1);
                        o.y = pk2(v2, v3);
                        int sboff = lrow * 256 + ((n * 32 + kg * 8) ^ ((lrow & 7) << 4));
                        *(uint2*)(sb + (sboff >> 1)) = o;
                    }
                    // linear 4KB store: 4 x (ds_read_b128 + global_store_dwordx4)
#pragma unroll
                    for (int i = 0; i < 4; i++) {
                        int R = i * 4 + (lane >> 4);
                        int B = ((lane & 15) * 16) ^ ((R & 7) << 4);
                        uint4 v = *(const uint4*)(sb + ((R * 256 + B) >> 1));
                        *(uint4*)(Out + wrow0 * 128 + i * 512 + lane * 8) = v;
                    }
                }
                __builtin_amdgcn_sched_barrier(0);
                ISSUE_SLOT(d, t + (long)DEPTH * G);
                __builtin_amdgcn_sched_barrier(0);
            }
        }
    }
}

// ---------------- fused Wi GEMM + fa conversion (r9 exact, 150us known-good) ----------
__global__ __launch_bounds__(512, 2) void gemm_wi(
    const float* __restrict__ FA, const u16* __restrict__ Wp,
    const float* __restrict__ bias, u16* __restrict__ fa16, u16* __restrict__ Out) {
    constexpr int KB = 5, KP = 160, TILE = 128;
    constexpr long NT = (N_ATOMS + TILE - 1) / TILE;
    constexpr int WSLOTS = KB * 8;
    constexpr int DEPTH = 2;
    constexpr int NWAIT = 23;
    __shared__ __align__(16) u16 WL[WSLOTS * 512];

    const int lane = threadIdx.x & 63;
    const int wave = threadIdx.x >> 6;
    const int lrow = lane & 15;
    const int kg   = lane >> 4;

    for (int s = wave; s < WSLOTS; s += 8) {
        int kb = s >> 3, n = s & 7;
        gl16(Wp + (n * 16 + lrow) * KP + kb * 32 + kg * 8, WL + s * 512);
    }
    asm volatile("s_waitcnt vmcnt(0)" ::: "memory");
    __syncthreads();

    float4 b4[8];
#pragma unroll
    for (int n = 0; n < 8; n++) b4[n] = *(const float4*)(bias + n * 16 + kg * 4);

    const int G  = gridDim.x;
    const long t0 = blockIdx.x;

    uint4 af32[DEPTH][4][2];
    uint4 a4[DEPTH];
    float a4s[DEPTH];

#define WI_ISSUE(d, t)                                                         \
    do {                                                                       \
        long r_ = (t) * TILE + wave * 16 + lrow;                               \
        if (r_ > N_ATOMS - 1) r_ = N_ATOMS - 1;                                \
        const float* p_ = FA + r_ * (long)ATOM_FDIM + kg * 8;                  \
        _Pragma("unroll") for (int kb = 0; kb < 4; kb++) {                     \
            af32[d][kb][0] = *(const uint4*)(p_ + kb * 32);                    \
            af32[d][kb][1] = *(const uint4*)(p_ + kb * 32 + 4);                \
        }                                                                      \
        if (kg == 0) {                                                         \
            const float* q_ = FA + r_ * (long)ATOM_FDIM + 128;                 \
            a4[d]  = *(const uint4*)(q_);                                      \
            a4s[d] = q_[4];                                                    \
        }                                                                      \
    } while (0)

#pragma unroll
    for (int d = 0; d < DEPTH; d++) WI_ISSUE(d, t0 + (long)d * G);
    __builtin_amdgcn_sched_barrier(0);

#pragma unroll 1
    for (long tt = t0; tt < NT; tt += (long)DEPTH * G) {
#pragma unroll
        for (int d = 0; d < DEPTH; d++) {
            long t = tt + (long)d * G;
            if (t < NT) {
                asm volatile("s_waitcnt vmcnt(%0)" :: "n"(NWAIT) : "memory");
                __builtin_amdgcn_sched_barrier(0);

                long r = t * TILE + wave * 16 + lrow;
                bool wr = (r < N_ATOMS);

                short8 frag[5];
#pragma unroll
                for (int kb = 0; kb < 4; kb++) {
                    float4 lo = __builtin_bit_cast(float4, af32[d][kb][0]);
                    float4 hi = __builtin_bit_cast(float4, af32[d][kb][1]);
                    uint4 pk;
                    pk.x = pk2(lo.x, lo.y);
                    pk.y = pk2(lo.z, lo.w);
                    pk.z = pk2(hi.x, hi.y);
                    pk.w = pk2(hi.z, hi.w);
                    frag[kb] = __builtin_bit_cast(short8, pk);
                }
                {
                    uint4 pk = (uint4){0, 0, 0, 0};
                    if (kg == 0) {
                        float4 q = __builtin_bit_cast(float4, a4[d]);
                        pk.x = pk2(q.x, q.y);
                        pk.y = pk2(q.z, q.w);
                        pk.z = pk2(a4s[d], 0.f);
                    }
                    frag[4] = __builtin_bit_cast(short8, pk);
                }

                f32x4 acc[8];
#pragma unroll
                for (int n = 0; n < 8; n++) acc[n] = (f32x4){0.f, 0.f, 0.f, 0.f};
#pragma unroll
                for (int kb = 0; kb < 5; kb++) {
#pragma unroll
                    for (int n = 0; n < 8; n++) {
                        short8 bf = *(const short8*)(WL + (kb * 8 + n) * 512 + lane * 8);
                        acc[n] = __builtin_amdgcn_mfma_f32_16x16x32_bf16(bf, frag[kb], acc[n], 0, 0, 0);
                    }
                }

                if (wr) {
#pragma unroll
                    for (int kb = 0; kb < 5; kb++)
                        *(uint4*)(fa16 + r * 160 + kb * 32 + kg * 8) = __builtin_bit_cast(uint4, frag[kb]);
#pragma unroll
                    for (int n = 0; n < 8; n++) {
                        uint2 o;
                        o.x = pk2(acc[n][0] + b4[n].x, acc[n][1] + b4[n].y);
                        o.y = pk2(acc[n][2] + b4[n].z, acc[n][3] + b4[n].w);
                        *(uint2*)(Out + r * 128 + n * 16 + kg * 4) = o;
                    }
                }
                __builtin_amdgcn_sched_barrier(0);
                WI_ISSUE(d, t + (long)DEPTH * G);
                __builtin_amdgcn_sched_barrier(0);
            }
        }
    }
#undef WI_ISSUE
}

// ---------------- readout: per-mol max over 20 atoms (w/ relu) then dot ffn_w ----------
__global__ __launch_bounds__(256) void readout(const u16* __restrict__ ah,
                                               const float* __restrict__ ffn_w,
                                               const float* __restrict__ ffn_b,
                                               float* __restrict__ out) {
    int mol  = blockIdx.x * 4 + (threadIdx.x >> 6);
    int lane = threadIdx.x & 63;
    if (mol >= N_MOLS) return;
    float m0 = -1e30f, m1 = -1e30f;
    const u16* base = ah + (long)mol * APM * 128 + 2 * lane;
#pragma unroll
    for (int a = 0; a < APM; a++) {
        u32 v = *(const u32*)(base + a * 128);
        m0 = fmaxf(m0, bf2f((u16)(v & 0xFFFFu)));
        m1 = fmaxf(m1, bf2f((u16)(v >> 16)));
    }
    m0 = fmaxf(m0, 0.f);
    m1 = fmaxf(m1, 0.f);
    float p = m0 * ffn_w[2 * lane] + m1 * ffn_w[2 * lane + 1];
#pragma unroll
    for (int off = 32; off > 0; off >>= 1) p += __shfl_down(p, off);
    if (lane == 0) out[mol] = p + ffn_b[0];
}

extern "C" void kernel_launch(void* const* d_in, const int* in_sizes, int n_in,
                              void* d_out, int out_size, void* d_ws, size_t ws_size,
                              hipStream_t stream) {
    const float* f_atoms = (const float*)d_in[0];
    const float* f_bonds = (const float*)d_in[1];
    const float* Wi_w = (const float*)d_in[2];
    const float* Wi_b = (const float*)d_in[3];
    const float* Wh_w = (const float*)d_in[4];
    const float* Wh_b = (const float*)d_in[5];
    const float* Wo_w = (const float*)d_in[6];
    const float* Wo_b = (const float*)d_in[7];
    const float* ffn_w = (const float*)d_in[8];
    const float* ffn_b = (const float*)d_in[9];
    const int* a2a = (const int*)d_in[10];
    const int* a2b = (const int*)d_in[11];
    float* out = (float*)d_out;

    char* ws = (char*)d_ws;
    u16* fa    = (u16*)(ws);                  // 160,000,000
    u16* xb    = (u16*)(ws + 160000000L);     // 128,000,000  (pre-relu x)
    u16* msgA  = (u16*)(ws + 288000000L);     // 128,000,000
    u16* msgB  = (u16*)(ws + 416000000L);     // 128,000,000
    u16* nsum  = (u16*)(ws + 544000000L);     // 128,000,000
    u16* nbond = (u16*)(ws + 672000000L);     // 32,000,000
    u16* Wip   = (u16*)(ws + 704000000L);     // 40960
    u16* Whp   = (u16*)(ws + 704040960L);     // 40960
    u16* Wop   = (u16*)(ws + 704081920L);     // 73728

    prep_weights<<<64, 256, 0, stream>>>(Wi_w, Wh_w, Wo_w, Wip, Whp, Wop);
    bond_gather<<<31250, 256, 0, stream>>>(f_bonds, a2b, nbond);

    // x = f_atoms @ Wi^T + b (pre-relu); also emits padded bf16 fa
    gemm_wi<<<256, 512, 0, stream>>>(f_atoms, Wip, Wi_b, fa, xb);

    // depth 1: A0=nsum (DMA), A1=nbond (reg), X=xb (reg)
    gather_relu_sum<<<31250, 256, 0, stream>>>(xb, a2a, nsum);
    gemm_dma<4, 1, true, true, 8><<<256, 512, 0, stream>>>(
        nsum, 128, nbond, 32, Whp, Wh_b, xb, msgA);
    // depth 2
    gather_relu_sum<<<31250, 256, 0, stream>>>(msgA, a2a, nsum);
    gemm_dma<4, 1, true, true, 8><<<256, 512, 0, stream>>>(
        nsum, 128, nbond, 32, Whp, Wh_b, xb, msgB);
    // final: [fa (DMA) | nsum (reg)] @ Wo^T -> atom_hiddens (pre-relu) into msgA
    gather_relu_sum<<<31250, 256, 0, stream>>>(msgB, a2a, nsum);
    gemm_dma<5, 4, false, true, 6><<<256, 384, 0, stream>>>(
        fa, 160, nsum, 128, Wop, Wo_b, (const u16*)nullptr, msgA);

    readout<<<6250, 256, 0, stream>>>(msgA, ffn_w, ffn_b, out);
}